// Round 4
// baseline (31.409 us; speedup 1.0000x reference)
//
#include <hip/hip_runtime.h>
#include <math.h>

#define TT   256
#define TM1  255
#define QD   9
#define KD   5
#define NH   3
#define DD   15   // NH*KD
#define HID  75   // 5*DD
#define NR   18   // NH + DD reduce values

__device__ __forceinline__ float fast_rcp(float x) {
    return __builtin_amdgcn_rcpf(x);   // v_rcp_f32
}

template<int CTRL>
__device__ __forceinline__ float dpp_add(float x) {
    int y = __builtin_amdgcn_update_dpp(0, __float_as_int(x), CTRL, 0xf, 0xf, true);
    return x + __int_as_float(y);
}

// full-rate VALU wave64 sum; result valid in lane 63
__device__ __forceinline__ float wave_sum63(float x) {
    x = dpp_add<0x111>(x);  // row_shr:1
    x = dpp_add<0x112>(x);  // row_shr:2
    x = dpp_add<0x114>(x);  // row_shr:4
    x = dpp_add<0x118>(x);  // row_shr:8
    x = dpp_add<0x142>(x);  // row_bcast:15
    x = dpp_add<0x143>(x);  // row_bcast:31
    return x;
}

__device__ __forceinline__ float bcast(float x, int l) {
    return __int_as_float(__builtin_amdgcn_readlane(__float_as_int(x), l));
}

__global__ __launch_bounds__(64, 8)
void fused_block_kernel(const float* __restrict__ state,   // (32,256,7)
                        const float* __restrict__ action,  // (32,256,2)
                        const float* __restrict__ Wk,      // (15,5)
                        const float* __restrict__ Wq,      // (15,9)
                        const float* __restrict__ Wv,      // (15,5)
                        const float* __restrict__ att_bias,// (5)
                        const float* __restrict__ Wscore,  // (1,5)
                        const float* __restrict__ bscore,  // (1)
                        const float* __restrict__ g1,
                        const float* __restrict__ beta1,
                        const float* __restrict__ W1,      // (75,15)
                        const float* __restrict__ bff1,    // (75)
                        const float* __restrict__ W2,      // (15,75)
                        const float* __restrict__ bff2,    // (15)
                        const float* __restrict__ g2,
                        const float* __restrict__ beta2,
                        float* __restrict__ out)           // (32,256,15)
{
    const int blk = blockIdx.x;        // b*256 + i
    const int b   = blk >> 8;
    const int qi  = blk & 255;
    const int m   = threadIdx.x;       // 0..63; neighbors m, m+64, m+128, m+192

    __shared__ __align__(16) float s_h[HID];   // MLP hidden

    const float* __restrict__ sb  = state + (size_t)b*TT*7;
    const float* __restrict__ sti = sb + qi*7;
    const float si0 = sti[0], si1 = sti[1], si2 = sti[2], si3 = sti[3];

    // ---- query projection (+att_bias folded) in lanes 0..14, SGPR broadcast
    float qv = 0.0f;
    if (m < DD) {
        float acc = att_bias[m % KD];
        #pragma unroll
        for (int k = 0; k < 7; k++) acc = fmaf(Wq[m*QD+k], sti[k], acc);
        acc = fmaf(Wq[m*QD+7], action[((size_t)b*TT+qi)*2 + 0], acc);
        acc = fmaf(Wq[m*QD+8], action[((size_t)b*TT+qi)*2 + 1], acc);
        qv = acc;
    }
    float qb[DD];
    #pragma unroll
    for (int d = 0; d < DD; d++) qb[d] = bcast(qv, d);

    // score constants: sc = C - 2*sum_kk wsc_kk/(e_kk+1),  C = bscore + sum wsc
    float wsc2[KD];
    float C = bscore[0];
    #pragma unroll
    for (int kk = 0; kk < KD; kk++) { float w = Wscore[kk]; wsc2[kk] = -2.0f*w; C += w; }

    // ---- per-pair phase: 4 neighbors/thread, branchless, dbuf'd row loads
    float red[NR];
    #pragma unroll
    for (int n = 0; n < NR; n++) red[n] = 0.0f;

    float nrow[7];
    {
        const int j0 = m + (m >= qi ? 1 : 0);   // always <= 255
        #pragma unroll
        for (int k = 0; k < 7; k++) nrow[k] = sb[j0*7 + k];
    }

    #pragma unroll
    for (int pp = 0; pp < 4; pp++) {
        float crow[7];
        #pragma unroll
        for (int k = 0; k < 7; k++) crow[k] = nrow[k];
        if (pp < 3) {
            const int mmn = m + (pp+1)*64;
            int jn = mmn + (mmn >= qi ? 1 : 0);
            jn = (jn <= TM1) ? jn : TM1;
            #pragma unroll
            for (int k = 0; k < 7; k++) nrow[k] = sb[jn*7 + k];
        }
        const int   mm = m + pp*64;
        const float Cp = (mm < TM1) ? C : -100.0f;   // invalid lane -> p = 0

        const float d0 = crow[0]-si0, d1 = crow[1]-si1;
        const float d2 = crow[2]-si2, d3 = crow[3]-si3;
        // ref rotates by ang = pi/2 - theta_j: cos(ang)=sin(th), sin(ang)=cos(th)
        const float th = crow[6];
        const float cs = __sinf(th);    // native v_sin
        const float sn = __cosf(th);    // native v_cos
        const float xr0 = d0*cs - d1*sn, yr0 = d0*sn + d1*cs;
        const float xr1 = d2*cs - d3*sn, yr1 = d2*sn + d3*cs;
        const float s2   = fmaxf(fmaf(xr0, xr0, yr0*yr0), 1e-12f); // NaN-proof
        const float rinv = __builtin_amdgcn_rsqf(s2);
        const float r    = s2 * rinv;
        const float rt   = fast_rcp(1.0f + __expf(fmaf(5.0f, r, -2.0f)));
        const float kv0 = xr0*rinv, kv1 = yr0*rinv;  // kv2=xr1, kv3=yr1, kv4=rt

        #pragma unroll
        for (int h = 0; h < NH; h++) {
            float sc = Cp;
            #pragma unroll
            for (int kk = 0; kk < KD; kk++) {
                const int d = h*KD + kk;
                float a = qb[d];
                a = fmaf(Wk[d*KD+0], kv0, a);
                a = fmaf(Wk[d*KD+1], kv1, a);
                a = fmaf(Wk[d*KD+2], xr1, a);
                a = fmaf(Wk[d*KD+3], yr1, a);
                a = fmaf(Wk[d*KD+4], rt , a);
                // tanh folded: wsc*tanh(a) = wsc - 2*wsc/(exp(2a)+1)
                sc = fmaf(wsc2[kk], fast_rcp(__expf(a + a) + 1.0f), sc);
            }
            const float p = __expf(sc);   // |sc| bounded -> no max-subtraction
            red[h] += p;
            red[NH+h*KD+0] = fmaf(p, kv0, red[NH+h*KD+0]);
            red[NH+h*KD+1] = fmaf(p, kv1, red[NH+h*KD+1]);
            red[NH+h*KD+2] = fmaf(p, xr1, red[NH+h*KD+2]);
            red[NH+h*KD+3] = fmaf(p, yr1, red[NH+h*KD+3]);
            red[NH+h*KD+4] = fmaf(p, rt , red[NH+h*KD+4]);
        }
    }

    // ---- single-wave reduction + SGPR broadcast of the 18 totals
    #pragma unroll
    for (int n = 0; n < NR; n++) red[n] = wave_sum63(red[n]);
    float fin[NR];
    #pragma unroll
    for (int n = 0; n < NR; n++) fin[n] = bcast(red[n], 63);

    // ---- Wv projection (deferred, linear) + softmax normalize (lanes 0..14)
    float xm = 0.0f;
    if (m < DD) {
        const int h = m / KD;
        float acc = 0.0f;
        #pragma unroll
        for (int c = 0; c < KD; c++) acc = fmaf(Wv[m*KD+c], fin[NH+h*KD+c], acc);
        xm = acc * fast_rcp(fin[h]);
    }

    // ---- LN1 across lanes 0..15 (lane 15 contributes 0)
    float s1 = xm, sq = xm*xm;
    #pragma unroll
    for (int off = 8; off >= 1; off >>= 1) {
        s1 += __shfl_xor(s1, off, 16);
        sq += __shfl_xor(sq, off, 16);
    }
    const float mu1   = s1 * (1.0f/DD);
    const float rstd1 = rsqrtf(sq * (1.0f/DD) - mu1*mu1 + 1e-5f);
    float xln = 0.0f;
    if (m < DD) xln = (xm - mu1) * rstd1 * g1[m] + beta1[m];

    // broadcast LN1 output to uniform scalars for the MLP
    float xs[DD];
    #pragma unroll
    for (int d = 0; d < DD; d++) xs[d] = bcast(xln, d);

    // ---- MLP layer 1: 75 hidden units over 64 lanes (lanes 0..10 do two)
    {
        float h0 = bff1[m];
        #pragma unroll
        for (int k = 0; k < DD; k++) h0 = fmaf(W1[m*DD+k], xs[k], h0);
        s_h[m] = fmaxf(h0, 0.0f);
        if (m < HID-64) {
            float h1 = bff1[m+64];
            #pragma unroll
            for (int k = 0; k < DD; k++) h1 = fmaf(W1[(m+64)*DD+k], xs[k], h1);
            s_h[m+64] = fmaxf(h1, 0.0f);
        }
    }
    __syncthreads();

    // ---- MLP layer 2: 3 chunks x 25 over lanes (c2<3), combine via shfl
    const int c2 = m >> 4;                  // 0..3
    const int d2 = m & 15;                  // 0..15
    const int cc = (c2 < 3) ? c2 : 2;       // clamp for safe addressing
    const int dc = (d2 < DD) ? d2 : 0;
    float acc2 = 0.0f;
    #pragma unroll
    for (int k = 0; k < 25; k++)
        acc2 = fmaf(W2[dc*HID + cc*25 + k], s_h[cc*25 + k], acc2);
    acc2 = (c2 < 3) ? acc2 : 0.0f;          // kill duplicated chunk
    acc2 += __shfl_xor(acc2, 16);
    acc2 += __shfl_xor(acc2, 32);           // lanes 0..15 now hold full sums

    // ---- residual + LN2 + store
    float x2 = 0.0f;
    if (m < DD) x2 = xln + bff2[m] + acc2;  // residual uses post-LN1 x
    float t1 = x2, t2 = x2*x2;
    #pragma unroll
    for (int off = 8; off >= 1; off >>= 1) {
        t1 += __shfl_xor(t1, off, 16);
        t2 += __shfl_xor(t2, off, 16);
    }
    const float mu2   = t1 * (1.0f/DD);
    const float rstd2 = rsqrtf(t2 * (1.0f/DD) - mu2*mu2 + 1e-5f);
    if (m < DD)
        out[(size_t)blk*DD + m] = (x2 - mu2) * rstd2 * g2[m] + beta2[m];
}

extern "C" void kernel_launch(void* const* d_in, const int* in_sizes, int n_in,
                              void* d_out, int out_size, void* d_ws, size_t ws_size,
                              hipStream_t stream) {
    const float* state    = (const float*)d_in[0];
    const float* action   = (const float*)d_in[1];
    const float* Wk       = (const float*)d_in[2];
    const float* Wq       = (const float*)d_in[3];
    const float* Wv       = (const float*)d_in[4];
    const float* att_bias = (const float*)d_in[5];
    const float* Wscore   = (const float*)d_in[6];
    const float* bscore   = (const float*)d_in[7];
    const float* g1       = (const float*)d_in[8];
    const float* beta1    = (const float*)d_in[9];
    const float* W1       = (const float*)d_in[10];
    const float* bff1     = (const float*)d_in[11];
    const float* W2       = (const float*)d_in[12];
    const float* bff2     = (const float*)d_in[13];
    const float* g2       = (const float*)d_in[14];
    const float* beta2    = (const float*)d_in[15];
    float* out = (float*)d_out;

    dim3 grid(32 * 256);
    dim3 block(64);
    fused_block_kernel<<<grid, block, 0, stream>>>(
        state, action, Wk, Wq, Wv, att_bias, Wscore, bscore,
        g1, beta1, W1, bff1, W2, bff2, g2, beta2, out);
}

// Round 5
// 27.838 us; speedup vs baseline: 1.1283x; 1.1283x over previous
//
#include <hip/hip_runtime.h>
#include <math.h>

#define TT   256
#define TM1  255
#define QD   9
#define KD   5
#define NH   3
#define DD   15   // NH*KD
#define HID  75   // 5*DD
#define NR   18   // NH + DD reduce values

__device__ __forceinline__ float fast_rcp(float x) {
    return __builtin_amdgcn_rcpf(x);   // v_rcp_f32
}

template<int CTRL>
__device__ __forceinline__ float dpp_add(float x) {
    int y = __builtin_amdgcn_update_dpp(0, __float_as_int(x), CTRL, 0xf, 0xf, true);
    return x + __int_as_float(y);
}

// full-rate VALU wave64 sum; result valid in lane 63
__device__ __forceinline__ float wave_sum63(float x) {
    x = dpp_add<0x111>(x);  // row_shr:1
    x = dpp_add<0x112>(x);  // row_shr:2
    x = dpp_add<0x114>(x);  // row_shr:4
    x = dpp_add<0x118>(x);  // row_shr:8
    x = dpp_add<0x142>(x);  // row_bcast:15
    x = dpp_add<0x143>(x);  // row_bcast:31
    return x;
}

__device__ __forceinline__ float bcast(float x, int l) {
    return __int_as_float(__builtin_amdgcn_readlane(__float_as_int(x), l));
}

__global__ __launch_bounds__(256)
void fused_block_kernel(const float* __restrict__ state,   // (32,256,7)
                        const float* __restrict__ action,  // (32,256,2)
                        const float* __restrict__ Wk,      // (15,5)
                        const float* __restrict__ Wq,      // (15,9)
                        const float* __restrict__ Wv,      // (15,5)
                        const float* __restrict__ att_bias,// (5)
                        const float* __restrict__ Wscore,  // (1,5)
                        const float* __restrict__ bscore,  // (1)
                        const float* __restrict__ g1,
                        const float* __restrict__ beta1,
                        const float* __restrict__ W1,      // (75,15)
                        const float* __restrict__ bff1,    // (75)
                        const float* __restrict__ W2,      // (15,75)
                        const float* __restrict__ bff2,    // (15)
                        const float* __restrict__ g2,
                        const float* __restrict__ beta2,
                        float* __restrict__ out)           // (32,256,15)
{
    const int tid  = threadIdx.x;
    const int lane = tid & 63;
    const int wv   = __builtin_amdgcn_readfirstlane(tid >> 6);  // SGPR wave id
    const int qgrp = blockIdx.x * 4 + wv;    // global query index (b*256+qi)
    const int b    = qgrp >> 8;
    const int qi   = qgrp & 255;             // uniform per wave -> scalar

    __shared__ float s_h[4][76];             // per-wave MLP hidden slice

    const float* __restrict__ sb  = state + (size_t)b*TT*7;
    const float* __restrict__ sti = sb + qi*7;
    const float si0 = sti[0], si1 = sti[1], si2 = sti[2], si3 = sti[3];

    // ---- query projection (+att_bias folded) lanes 0..14; doubled broadcast
    float qv = 0.0f;
    if (lane < DD) {
        float acc = att_bias[lane % KD];
        #pragma unroll
        for (int k = 0; k < 7; k++) acc = fmaf(Wq[lane*QD+k], sti[k], acc);
        acc = fmaf(Wq[lane*QD+7], action[((size_t)b*TT+qi)*2 + 0], acc);
        acc = fmaf(Wq[lane*QD+8], action[((size_t)b*TT+qi)*2 + 1], acc);
        qv = acc;
    }
    float qb2[DD];                            // 2*(q+bias) for exp(2a)
    #pragma unroll
    for (int d = 0; d < DD; d++) qb2[d] = bcast(qv + qv, d);

    // score constants: sc = C - 2*sum_kk wsc_kk/(exp(2a)+1),  C = bscore + sum wsc
    float wsc2[KD];
    float C = bscore[0];
    #pragma unroll
    for (int kk = 0; kk < KD; kk++) { float w = Wscore[kk]; wsc2[kk] = -2.0f*w; C += w; }

    // ---- per-pair phase: 4 neighbors per lane, accumulate in registers
    float red[NR];
    #pragma unroll
    for (int n = 0; n < NR; n++) red[n] = 0.0f;

    #pragma unroll
    for (int pp = 0; pp < 4; pp++) {
        const int mm = lane + pp*64;
        if (mm < TM1) {
            const int jj = mm + (mm >= qi ? 1 : 0);
            const float* stj = sb + jj*7;
            const float d0 = stj[0]-si0, d1 = stj[1]-si1;
            const float d2 = stj[2]-si2, d3 = stj[3]-si3;
            // ref rotates by ang = pi/2 - theta_j: cos(ang)=sin(th), sin(ang)=cos(th)
            const float th = stj[6];
            const float cs = __sinf(th);     // native v_sin
            const float sn = __cosf(th);     // native v_cos
            const float xr0 = d0*cs - d1*sn, yr0 = d0*sn + d1*cs;
            const float xr1 = d2*cs - d3*sn, yr1 = d2*sn + d3*cs;
            const float s2   = fmaxf(fmaf(xr0, xr0, yr0*yr0), 1e-12f);
            const float rinv = __builtin_amdgcn_rsqf(s2);
            const float r    = s2 * rinv;
            const float rt   = fast_rcp(1.0f + __expf(fmaf(5.0f, r, -2.0f)));
            const float kv0 = xr0*rinv, kv1 = yr0*rinv;  // kv2=xr1 kv3=yr1 kv4=rt
            // pre-doubled features so the tanh exp argument needs no final *2
            const float f0 = kv0+kv0, f1 = kv1+kv1, f2 = xr1+xr1,
                        f3 = yr1+yr1, f4 = rt+rt;

            #pragma unroll
            for (int h = 0; h < NH; h++) {
                float sc = C;
                #pragma unroll
                for (int kk = 0; kk < KD; kk++) {
                    const int d = h*KD + kk;
                    float a = qb2[d];
                    a = fmaf(Wk[d*KD+0], f0, a);
                    a = fmaf(Wk[d*KD+1], f1, a);
                    a = fmaf(Wk[d*KD+2], f2, a);
                    a = fmaf(Wk[d*KD+3], f3, a);
                    a = fmaf(Wk[d*KD+4], f4, a);
                    // tanh folded: wsc*tanh = wsc - 2*wsc/(exp(2a)+1)
                    sc = fmaf(wsc2[kk], fast_rcp(__expf(a) + 1.0f), sc);
                }
                const float p = __expf(sc);  // |sc| bounded -> no max-subtraction
                red[h] += p;
                red[NH+h*KD+0] = fmaf(p, kv0, red[NH+h*KD+0]);
                red[NH+h*KD+1] = fmaf(p, kv1, red[NH+h*KD+1]);
                red[NH+h*KD+2] = fmaf(p, xr1, red[NH+h*KD+2]);
                red[NH+h*KD+3] = fmaf(p, yr1, red[NH+h*KD+3]);
                red[NH+h*KD+4] = fmaf(p, rt , red[NH+h*KD+4]);
            }
        }
    }

    // ---- single-wave reduction + SGPR broadcast of the 18 totals
    #pragma unroll
    for (int n = 0; n < NR; n++) red[n] = wave_sum63(red[n]);
    float fin[NR];
    #pragma unroll
    for (int n = 0; n < NR; n++) fin[n] = bcast(red[n], 63);

    // ---- Wv projection (deferred, linear) + softmax normalize (lanes 0..14)
    float xm = 0.0f;
    if (lane < DD) {
        const int h = lane / KD;
        float acc = 0.0f;
        #pragma unroll
        for (int c = 0; c < KD; c++) acc = fmaf(Wv[lane*KD+c], fin[NH+h*KD+c], acc);
        xm = acc * fast_rcp(fin[h]);
    }

    // ---- LN1 across lanes 0..15 (lane 15 contributes 0)
    float s1 = xm, sq = xm*xm;
    #pragma unroll
    for (int off = 8; off >= 1; off >>= 1) {
        s1 += __shfl_xor(s1, off, 16);
        sq += __shfl_xor(sq, off, 16);
    }
    const float mu1   = s1 * (1.0f/DD);
    const float rstd1 = rsqrtf(sq * (1.0f/DD) - mu1*mu1 + 1e-5f);
    float xln = 0.0f;
    if (lane < DD) xln = (xm - mu1) * rstd1 * g1[lane] + beta1[lane];

    // broadcast LN1 output to uniform scalars for the MLP
    float xs[DD];
    #pragma unroll
    for (int d = 0; d < DD; d++) xs[d] = bcast(xln, d);

    // ---- MLP layer 1: 75 hidden units over 64 lanes (lanes 0..10 do two)
    {
        float h0 = bff1[lane];
        #pragma unroll
        for (int k = 0; k < DD; k++) h0 = fmaf(W1[lane*DD+k], xs[k], h0);
        s_h[wv][lane] = fmaxf(h0, 0.0f);
        if (lane < HID-64) {
            float h1 = bff1[lane+64];
            #pragma unroll
            for (int k = 0; k < DD; k++) h1 = fmaf(W1[(lane+64)*DD+k], xs[k], h1);
            s_h[wv][lane+64] = fmaxf(h1, 0.0f);
        }
    }
    // same-wave LDS producer/consumer: no barrier needed (compiler waits lgkmcnt)

    // ---- MLP layer 2: 3 chunks x 25 over lane groups, combine via shfl
    const int c2  = lane >> 4;               // 0..3
    const int d2c = lane & 15;
    const int cc  = (c2 < 3) ? c2 : 2;       // clamp for safe addressing
    const int dc  = (d2c < DD) ? d2c : 0;
    float acc2 = 0.0f;
    #pragma unroll
    for (int k = 0; k < 25; k++)
        acc2 = fmaf(W2[dc*HID + cc*25 + k], s_h[wv][cc*25 + k], acc2);
    acc2 = (c2 < 3) ? acc2 : 0.0f;           // kill duplicated chunk
    acc2 += __shfl_xor(acc2, 16);
    acc2 += __shfl_xor(acc2, 32);            // lanes 0..15 hold full sums

    // ---- residual + LN2 + store
    float x2 = 0.0f;
    if (lane < DD) x2 = xln + bff2[lane] + acc2;   // residual uses post-LN1 x
    float t1 = x2, t2 = x2*x2;
    #pragma unroll
    for (int off = 8; off >= 1; off >>= 1) {
        t1 += __shfl_xor(t1, off, 16);
        t2 += __shfl_xor(t2, off, 16);
    }
    const float mu2   = t1 * (1.0f/DD);
    const float rstd2 = rsqrtf(t2 * (1.0f/DD) - mu2*mu2 + 1e-5f);
    if (lane < DD)
        out[(size_t)qgrp*DD + lane] = (x2 - mu2) * rstd2 * g2[lane] + beta2[lane];
}

extern "C" void kernel_launch(void* const* d_in, const int* in_sizes, int n_in,
                              void* d_out, int out_size, void* d_ws, size_t ws_size,
                              hipStream_t stream) {
    const float* state    = (const float*)d_in[0];
    const float* action   = (const float*)d_in[1];
    const float* Wk       = (const float*)d_in[2];
    const float* Wq       = (const float*)d_in[3];
    const float* Wv       = (const float*)d_in[4];
    const float* att_bias = (const float*)d_in[5];
    const float* Wscore   = (const float*)d_in[6];
    const float* bscore   = (const float*)d_in[7];
    const float* g1       = (const float*)d_in[8];
    const float* beta1    = (const float*)d_in[9];
    const float* W1       = (const float*)d_in[10];
    const float* bff1     = (const float*)d_in[11];
    const float* W2       = (const float*)d_in[12];
    const float* bff2     = (const float*)d_in[13];
    const float* g2       = (const float*)d_in[14];
    const float* beta2    = (const float*)d_in[15];
    float* out = (float*)d_out;

    dim3 grid(32 * 256 / 4);   // 4 queries (waves) per block
    dim3 block(256);
    fused_block_kernel<<<grid, block, 0, stream>>>(
        state, action, Wk, Wq, Wv, att_bias, Wscore, bscore,
        g1, beta1, W1, bff1, W2, bff2, g2, beta2, out);
}

// Round 6
// 26.303 us; speedup vs baseline: 1.1941x; 1.0584x over previous
//
#include <hip/hip_runtime.h>
#include <math.h>

#define TT   256
#define TM1  255
#define QD   9
#define KD   5
#define NH   3
#define DD   15   // NH*KD
#define HID  75   // 5*DD
#define NR   18   // NH + DD reduce values

#define K2E  2.8853900817779268f   // 2*log2(e)
#define L2E  1.4426950408889634f   // log2(e)
#define INVK 0.34657359027997264f  // 1/K2E = ln(2)/2

__device__ __forceinline__ float fast_rcp(float x) {
    return __builtin_amdgcn_rcpf(x);   // v_rcp_f32
}

__device__ __forceinline__ float exp2_raw(float x) {   // v_exp_f32: 2^x
    float r; asm("v_exp_f32 %0, %1" : "=v"(r) : "v"(x)); return r;
}

template<int CTRL>
__device__ __forceinline__ float dpp_add(float x) {
    int y = __builtin_amdgcn_update_dpp(0, __float_as_int(x), CTRL, 0xf, 0xf, true);
    return x + __int_as_float(y);
}

// full-rate VALU wave64 sum; result valid in lane 63
__device__ __forceinline__ float wave_sum63(float x) {
    x = dpp_add<0x111>(x);  // row_shr:1
    x = dpp_add<0x112>(x);  // row_shr:2
    x = dpp_add<0x114>(x);  // row_shr:4
    x = dpp_add<0x118>(x);  // row_shr:8
    x = dpp_add<0x142>(x);  // row_bcast:15
    x = dpp_add<0x143>(x);  // row_bcast:31
    return x;
}

__device__ __forceinline__ float bcast(float x, int l) {
    return __int_as_float(__builtin_amdgcn_readlane(__float_as_int(x), l));
}

__global__ __launch_bounds__(256)
void fused_block_kernel(const float* __restrict__ state,   // (32,256,7)
                        const float* __restrict__ action,  // (32,256,2)
                        const float* __restrict__ Wk,      // (15,5)
                        const float* __restrict__ Wq,      // (15,9)
                        const float* __restrict__ Wv,      // (15,5)
                        const float* __restrict__ att_bias,// (5)
                        const float* __restrict__ Wscore,  // (1,5)
                        const float* __restrict__ bscore,  // (1)
                        const float* __restrict__ g1,
                        const float* __restrict__ beta1,
                        const float* __restrict__ W1,      // (75,15)
                        const float* __restrict__ bff1,    // (75)
                        const float* __restrict__ W2,      // (15,75)
                        const float* __restrict__ bff2,    // (15)
                        const float* __restrict__ g2,
                        const float* __restrict__ beta2,
                        float* __restrict__ out)           // (32,256,15)
{
    const int tid  = threadIdx.x;
    const int lane = tid & 63;
    const int wv   = __builtin_amdgcn_readfirstlane(tid >> 6);  // SGPR wave id
    const int qgrp = blockIdx.x * 4 + wv;    // global query index (b*256+qi)
    const int b    = qgrp >> 8;
    const int qi   = qgrp & 255;             // uniform per wave

    __shared__ float s_h[4][76];             // per-wave MLP hidden slice

    const float* __restrict__ sb  = state + (size_t)b*TT*7;
    const float* __restrict__ sti = sb + qi*7;

    // ---- issue ALL neighbor-row loads up front (branchless, clamped)
    float row[4][7];
    #pragma unroll
    for (int pp = 0; pp < 4; pp++) {
        const int mmp = lane + pp*64;
        int jj = mmp + (mmp >= qi ? 1 : 0);
        jj = (jj < TT) ? jj : (TT-1);
        const float* stj = sb + jj*7;
        #pragma unroll
        for (int k = 0; k < 7; k++) row[pp][k] = stj[k];
    }

    const float si0 = sti[0], si1 = sti[1], si2 = sti[2], si3 = sti[3];

    // ---- query projection (+att_bias folded) lanes 0..14; scaled by 2*log2e
    float qv = 0.0f;
    if (lane < DD) {
        float acc = att_bias[lane % KD];
        #pragma unroll
        for (int k = 0; k < 7; k++) acc = fmaf(Wq[lane*QD+k], sti[k], acc);
        acc = fmaf(Wq[lane*QD+7], action[((size_t)b*TT+qi)*2 + 0], acc);
        acc = fmaf(Wq[lane*QD+8], action[((size_t)b*TT+qi)*2 + 1], acc);
        qv = acc * K2E;
    }
    float qb2[DD];
    #pragma unroll
    for (int d = 0; d < DD; d++) qb2[d] = bcast(qv, d);

    // score constants in exp2 domain:
    //   p = exp2(C2 + sum_kk w2_kk * sigma_kk), sigma = rcp(exp2(a2)+1)
    float w2[KD];
    float Cn = bscore[0];
    #pragma unroll
    for (int kk = 0; kk < KD; kk++) { float w = Wscore[kk]; w2[kk] = -K2E*w; Cn += w; }
    const float C2 = L2E * Cn;

    // ---- geometry for all 4 pairs -> pre-scaled features f* = K2E * kv
    float f0[4], f1[4], f2[4], f3[4], f4[4], Cp[4];
    #pragma unroll
    for (int pp = 0; pp < 4; pp++) {
        const float d0 = row[pp][0]-si0, d1 = row[pp][1]-si1;
        const float d2 = row[pp][2]-si2, d3 = row[pp][3]-si3;
        // ref rotates by ang = pi/2 - theta_j: cos(ang)=sin(th), sin(ang)=cos(th)
        const float th = row[pp][6];
        const float cs = __sinf(th);     // native
        const float sn = __cosf(th);     // native
        const float xr0 = d0*cs - d1*sn, yr0 = d0*sn + d1*cs;
        const float xr1 = d2*cs - d3*sn, yr1 = d2*sn + d3*cs;
        const float s2   = fmaxf(fmaf(xr0, xr0, yr0*yr0), 1e-12f); // NaN-proof
        const float rinv = __builtin_amdgcn_rsqf(s2);
        const float r    = s2 * rinv;
        // sigmoid(1-5(r-0.2)) = rcp(1 + exp2(5*log2e*r - 2*log2e))
        const float rt   = fast_rcp(1.0f + exp2_raw(fmaf(7.213475204444817f, r,
                                                         -2.8853900817779268f)));
        const float t = K2E * rinv;
        f0[pp] = t * xr0;
        f1[pp] = t * yr0;
        f2[pp] = K2E * xr1;
        f3[pp] = K2E * yr1;
        f4[pp] = K2E * rt;
        const int mm = lane + pp*64;
        Cp[pp] = (mm < TM1) ? C2 : -100.0f;   // invalid pair -> p = 2^-100 ~ 0
    }

    // ---- scores + accumulate (all 60 tanh terms independent)
    float red[NR];
    #pragma unroll
    for (int n = 0; n < NR; n++) red[n] = 0.0f;

    #pragma unroll
    for (int pp = 0; pp < 4; pp++) {
        #pragma unroll
        for (int h = 0; h < NH; h++) {
            float sc = Cp[pp];
            #pragma unroll
            for (int kk = 0; kk < KD; kk++) {
                const int d = h*KD + kk;
                float a = qb2[d];
                a = fmaf(Wk[d*KD+0], f0[pp], a);
                a = fmaf(Wk[d*KD+1], f1[pp], a);
                a = fmaf(Wk[d*KD+2], f2[pp], a);
                a = fmaf(Wk[d*KD+3], f3[pp], a);
                a = fmaf(Wk[d*KD+4], f4[pp], a);
                // wsc*tanh(a_nat) = wsc - 2*wsc*rcp(exp2(a2)+1), folded into C2/w2
                sc = fmaf(w2[kk], fast_rcp(exp2_raw(a) + 1.0f), sc);
            }
            const float p = exp2_raw(sc);   // bounded |sc| -> no max-subtraction
            red[h] += p;
            red[NH+h*KD+0] = fmaf(p, f0[pp], red[NH+h*KD+0]);
            red[NH+h*KD+1] = fmaf(p, f1[pp], red[NH+h*KD+1]);
            red[NH+h*KD+2] = fmaf(p, f2[pp], red[NH+h*KD+2]);
            red[NH+h*KD+3] = fmaf(p, f3[pp], red[NH+h*KD+3]);
            red[NH+h*KD+4] = fmaf(p, f4[pp], red[NH+h*KD+4]);
        }
    }

    // ---- single-wave reduction + broadcast of the 18 totals
    #pragma unroll
    for (int n = 0; n < NR; n++) red[n] = wave_sum63(red[n]);
    float fin[NR];
    #pragma unroll
    for (int n = 0; n < NR; n++) fin[n] = bcast(red[n], 63);

    // ---- Wv projection (deferred, linear) + softmax normalize (lanes 0..14)
    // fin's value part carries factor K2E -> un-scale by INVK
    float xm = 0.0f;
    if (lane < DD) {
        const int h = lane / KD;
        float acc = 0.0f;
        #pragma unroll
        for (int c = 0; c < KD; c++) acc = fmaf(Wv[lane*KD+c], fin[NH+h*KD+c], acc);
        xm = acc * fast_rcp(fin[h]) * INVK;
    }

    // ---- LN1 across lanes 0..15 (lane 15 contributes 0)
    float s1 = xm, sq = xm*xm;
    #pragma unroll
    for (int off = 8; off >= 1; off >>= 1) {
        s1 += __shfl_xor(s1, off, 16);
        sq += __shfl_xor(sq, off, 16);
    }
    const float mu1   = s1 * (1.0f/DD);
    const float rstd1 = rsqrtf(sq * (1.0f/DD) - mu1*mu1 + 1e-5f);
    float xln = 0.0f;
    if (lane < DD) xln = (xm - mu1) * rstd1 * g1[lane] + beta1[lane];

    // broadcast LN1 output for the MLP
    float xs[DD];
    #pragma unroll
    for (int d = 0; d < DD; d++) xs[d] = bcast(xln, d);

    // ---- MLP layer 1: 75 hidden units over 64 lanes (lanes 0..10 do two)
    {
        float h0 = bff1[lane];
        #pragma unroll
        for (int k = 0; k < DD; k++) h0 = fmaf(W1[lane*DD+k], xs[k], h0);
        s_h[wv][lane] = fmaxf(h0, 0.0f);
        if (lane < HID-64) {
            float h1 = bff1[lane+64];
            #pragma unroll
            for (int k = 0; k < DD; k++) h1 = fmaf(W1[(lane+64)*DD+k], xs[k], h1);
            s_h[wv][lane+64] = fmaxf(h1, 0.0f);
        }
    }
    // same-wave LDS producer/consumer: compiler inserts lgkmcnt wait

    // ---- MLP layer 2: 3 chunks x 25 over lane groups, combine via shfl
    const int c2  = lane >> 4;               // 0..3
    const int d2c = lane & 15;
    const int cc  = (c2 < 3) ? c2 : 2;       // clamp for safe addressing
    const int dc  = (d2c < DD) ? d2c : 0;
    float acc2 = 0.0f;
    #pragma unroll
    for (int k = 0; k < 25; k++)
        acc2 = fmaf(W2[dc*HID + cc*25 + k], s_h[wv][cc*25 + k], acc2);
    acc2 = (c2 < 3) ? acc2 : 0.0f;           // kill duplicated chunk
    acc2 += __shfl_xor(acc2, 16);
    acc2 += __shfl_xor(acc2, 32);            // lanes 0..15 hold full sums

    // ---- residual + LN2 + store
    float x2 = 0.0f;
    if (lane < DD) x2 = xln + bff2[lane] + acc2;   // residual uses post-LN1 x
    float t1 = x2, t2 = x2*x2;
    #pragma unroll
    for (int off = 8; off >= 1; off >>= 1) {
        t1 += __shfl_xor(t1, off, 16);
        t2 += __shfl_xor(t2, off, 16);
    }
    const float mu2   = t1 * (1.0f/DD);
    const float rstd2 = rsqrtf(t2 * (1.0f/DD) - mu2*mu2 + 1e-5f);
    if (lane < DD)
        out[(size_t)qgrp*DD + lane] = (x2 - mu2) * rstd2 * g2[lane] + beta2[lane];
}

extern "C" void kernel_launch(void* const* d_in, const int* in_sizes, int n_in,
                              void* d_out, int out_size, void* d_ws, size_t ws_size,
                              hipStream_t stream) {
    const float* state    = (const float*)d_in[0];
    const float* action   = (const float*)d_in[1];
    const float* Wk       = (const float*)d_in[2];
    const float* Wq       = (const float*)d_in[3];
    const float* Wv       = (const float*)d_in[4];
    const float* att_bias = (const float*)d_in[5];
    const float* Wscore   = (const float*)d_in[6];
    const float* bscore   = (const float*)d_in[7];
    const float* g1       = (const float*)d_in[8];
    const float* beta1    = (const float*)d_in[9];
    const float* W1       = (const float*)d_in[10];
    const float* bff1     = (const float*)d_in[11];
    const float* W2       = (const float*)d_in[12];
    const float* bff2     = (const float*)d_in[13];
    const float* g2       = (const float*)d_in[14];
    const float* beta2    = (const float*)d_in[15];
    float* out = (float*)d_out;

    dim3 grid(32 * 256 / 4);   // 4 queries (waves) per block
    dim3 block(256);
    fused_block_kernel<<<grid, block, 0, stream>>>(
        state, action, Wk, Wq, Wv, att_bias, Wscore, bscore,
        g1, beta1, W1, bff1, W2, bff2, g2, beta2, out);
}